// Round 3
// baseline (1464.263 us; speedup 1.0000x reference)
//
#include <hip/hip_runtime.h>

#define RCUT 3.5f
#define TTAB 2048

static __device__ __forceinline__ float sigmoidf_(float x) { return 1.0f / (1.0f + expf(-x)); }
static __device__ __forceinline__ float siluf(float x) { return x / (1.0f + expf(-x)); }
// nan_to_num: 0 for NaN/Inf (bit-pattern test, fast-math immune)
static __device__ __forceinline__ float san(float x) {
    return ((__float_as_uint(x) & 0x7F800000u) != 0x7F800000u) ? x : 0.f;
}

// ---------------- radial table: d -> [coeff0,coeff1,coeff2,pad, W0..31, pad4] (stride 40) ----
__global__ void k_table(const float* means, const float* betas,
                        const float* rad_w1, const float* rad_b1,
                        const float* rad_w2, const float* rad_b2,
                        const float* ne_dw, const float* ne_db,
                        float* tab) {
    int i = blockIdx.x * blockDim.x + threadIdx.x;
    if (i >= TTAB) return;
    float d  = (float)i * (RCUT / (float)(TTAB - 1));
    float dc = fmaxf(d, 1e-6f);
    float C  = (dc < RCUT) ? 0.5f * (cosf(dc * (3.14159265358979f / RCUT)) + 1.0f) : 0.0f;
    float ex = expf(-(5.0f / RCUT) * dc);
    float rbf[8];
#pragma unroll
    for (int nn = 0; nn < 8; ++nn) {
        float b = fmaxf(betas[nn], 1e-6f);
        float t = ex - means[nn];
        rbf[nn] = C * expf(-b * t * t);
    }
    for (int l = 0; l < 3; ++l) {
        float acc = rad_b2[l];
        for (int h = 0; h < 256; ++h) {
            float cc = rad_b1[l * 256 + h];
#pragma unroll
            for (int nn = 0; nn < 8; ++nn) cc += rbf[nn] * rad_w1[(l * 8 + nn) * 256 + h];
            acc += siluf(cc) * rad_w2[l * 256 + h];
        }
        tab[i * 40 + l] = acc;
    }
    tab[i * 40 + 3] = 0.f;
    for (int c = 0; c < 32; ++c) {
        float wv = ne_db[c];
#pragma unroll
        for (int nn = 0; nn < 8; ++nn) wv += rbf[nn] * ne_dw[nn * 32 + c];
        tab[i * 40 + 4 + c] = wv * C;   // W includes cutoff_fn(d)
    }
    tab[i * 40 + 36] = tab[i * 40 + 37] = tab[i * 40 + 38] = tab[i * 40 + 39] = 0.f;
}

// ---------------- per-edge attrs: [ae0, ae1x,ae1y,ae1z, q00,q01,q02,q11, q12,q22, d, 0] ------
__global__ void k_edge(const float* pos, const float* alpha,
                       const int* ei, const float* tab, float* attrs,
                       int* cnt_dst, int* cnt_src, int E, int N) {
    int e = blockIdx.x * blockDim.x + threadIdx.x;
    if (e >= E) return;
    int sn = ei[e], dn = ei[E + e];
    float rx = pos[dn * 3]     - pos[sn * 3];
    float ry = pos[dn * 3 + 1] - pos[sn * 3 + 1];
    float rz = pos[dn * 3 + 2] - pos[sn * 3 + 2];
    float d = sqrtf(rx * rx + ry * ry + rz * rz + 1e-12f);
    float inv = 1.0f / d;
    rx *= inv; ry *= inv; rz *= inv;
    float u = fminf(d, RCUT) * ((float)(TTAB - 1) / RCUT);
    int i0 = (int)u; if (i0 > TTAB - 2) i0 = TTAB - 2;
    float f = u - (float)i0;
    const float* t0 = tab + i0 * 40;
    float c0 = t0[0] + f * (t0[40] - t0[0]);
    float c1 = t0[1] + f * (t0[41] - t0[1]);
    float c2 = t0[2] + f * (t0[42] - t0[2]);
    float al = alpha[e];
    float ae0 = san(al * c0);
    float k1 = 1.73205081f * al * c1;      // sqrt(3)*alpha*coeff1
    float k2 = al * c2;
    float e20 = san(5.47722558f * rx * ry * k2);                             // sqrt(30) xy
    float e21 = san(5.47722558f * ry * rz * k2);
    float e22 = san(1.58113883f * (2.f * rz * rz - rx * rx - ry * ry) * k2); // sqrt(2.5)
    float e23 = san(5.47722558f * rx * rz * k2);
    float e24 = san(2.73861279f * (rx * rx - ry * ry) * k2);                 // sqrt(7.5)
    const float S2 = 0.70710678f, S6 = 0.40824829f;
    float q00 = -S6 * e22 + S2 * e24;
    float q01 = S2 * e20;
    float q02 = S2 * e23;
    float q11 = -S6 * e22 - S2 * e24;
    float q12 = S2 * e21;
    float q22 = 2.f * S6 * e22;
    float4* ap = (float4*)(attrs + (size_t)e * 12);
    ap[0] = make_float4(ae0, san(k1 * rx), san(k1 * ry), san(k1 * rz));
    ap[1] = make_float4(q00, q01, q02, q11);
    ap[2] = make_float4(q12, q22, d, 0.f);
    atomicAdd(cnt_dst + dn, 1);
    atomicAdd(cnt_src + sn, 1);
}

// ---------------- exclusive scan (single block, 1024 threads) --------------------------------
__global__ void k_scan(const int* __restrict__ cnt, int* __restrict__ rowptr,
                       int* __restrict__ cursor, int n) {
    __shared__ int lds[1024];
    __shared__ int carry_s;
    int tid = threadIdx.x;
    if (tid == 0) carry_s = 0;
    __syncthreads();
    int nch = (n + 1023) >> 10;
    for (int ch = 0; ch < nch; ++ch) {
        int idx = (ch << 10) + tid;
        int val = (idx < n) ? cnt[idx] : 0;
        lds[tid] = val;
        __syncthreads();
        for (int off = 1; off < 1024; off <<= 1) {
            int t = (tid >= off) ? lds[tid - off] : 0;
            __syncthreads();
            lds[tid] += t;
            __syncthreads();
        }
        int incl = lds[tid];
        int excl = incl - val;
        int base = carry_s;
        if (idx < n) { rowptr[idx] = base + excl; cursor[idx] = base + excl; }
        __syncthreads();
        if (tid == 1023) carry_s = base + incl;
        __syncthreads();
    }
    if (tid == 0) rowptr[n] = carry_s;
}

__global__ void k_fill(const int* ei, int* cur_dst, int* cur_src,
                       int* eid_dst, int* eid_src, int E) {
    int e = blockIdx.x * blockDim.x + threadIdx.x;
    if (e >= E) return;
    int sn = ei[e], dn = ei[E + e];
    eid_dst[atomicAdd(cur_dst + dn, 1)] = e;
    eid_src[atomicAdd(cur_src + sn, 1)] = e;
}

// ---------------- aggr (gather by src) + initial node embed; v layout [c][m] c-major ---------
__global__ __launch_bounds__(256) void k_aggr(const int* row_src, const int* eid_src,
        const float* attrs, const float* tab, const int* ei, const int* z,
        const float* ne_emb, const float* atom_emb,
        const float* ne_cw, const float* ne_cb,
        float* sbuf, float* vbuf, int N, int E) {
    __shared__ float cat[4][64];
    int wv = threadIdx.x >> 6, lane = threadIdx.x & 63;
    int n = blockIdx.x * 4 + wv;
    bool act = n < N;
    float acc = 0.f;            // lanes 32..63: aggr channel (lane-32)
    int li = lane - 32;
    if (act && lane >= 32) {
        int r0 = row_src[n], r1 = row_src[n + 1];
        for (int k = r0; k < r1; ++k) {
            int e = eid_src[k];
            float dd = attrs[(size_t)e * 12 + 10];
            float u = fminf(dd, RCUT) * ((float)(TTAB - 1) / RCUT);
            int i0 = (int)u; if (i0 > TTAB - 2) i0 = TTAB - 2;
            float f = u - (float)i0;
            int dn = ei[E + e];
            int zd = z[dn];
            float w0 = tab[i0 * 40 + 4 + li], w1 = tab[(i0 + 1) * 40 + 4 + li];
            acc += (w0 + f * (w1 - w0)) * ne_emb[zd * 32 + li];
        }
    }
    float catv = 0.f;
    if (act) catv = (lane < 32) ? atom_emb[z[n] * 32 + lane] : acc;
    cat[wv][lane] = catv;       // cat = [atom_emb, aggr]
    __syncthreads();
    if (act && lane < 32) {
        float so = ne_cb[lane];
        for (int j = 0; j < 64; ++j) so += cat[wv][j] * ne_cw[j * 32 + lane];
        sbuf[n * 32 + lane] = so;
    }
    if (act && lane < 48) vbuf[n * 48 + lane] = 0.f;
}

// ---------------- per-layer message kernel (gather by dst, factored moments via LDS) ---------
// LDS layout per wave: [0:32) a0 | [32:128) a1(c*32+i) | [128:144) adv
//                      [144:192) a2(c*16+m) | [192:240) a3(c*16+m)
__global__ __launch_bounds__(256) void k_msg(const int* row_dst, const int* eid_dst,
        const int* ei, const float* attrs, const float* sbuf, const float* vbuf,
        const float* w00, const float* w110, const float* w01,
        const float* w10, const float* w12,
        float* msbuf, float* mvbuf, int N) {
    __shared__ float M[4][240];
    int wv = threadIdx.x >> 6, lane = threadIdx.x & 63;
    int n = blockIdx.x * 4 + wv;
    bool act = n < N;
    float a0 = 0.f, a1x = 0.f, a1y = 0.f, a1z = 0.f;
    float adv = 0.f, a2x = 0.f, a2y = 0.f, a2z = 0.f, a3x = 0.f, a3y = 0.f, a3z = 0.f;
    if (act && lane < 48) {
        int r0 = row_dst[n], r1 = row_dst[n + 1];
        int vv = lane - 32;
        for (int k = r0; k < r1; ++k) {
            int e = eid_dst[k];
            int srcn = ei[e];
            const float4* ap = (const float4*)(attrs + (size_t)e * 12);
            float4 A = ap[0], B = ap[1], Cc = ap[2];
            if (lane < 32) {
                float ssi = sbuf[srcn * 32 + lane];
                a0  += ssi * A.x;
                a1x += ssi * A.y; a1y += ssi * A.z; a1z += ssi * A.w;
            } else {
                const float* vp = vbuf + srcn * 48;
                float vx = vp[vv], vy = vp[16 + vv], vz = vp[32 + vv];
                adv += vx * A.y + vy * A.z + vz * A.w;
                a2x += vx * A.x; a2y += vy * A.x; a2z += vz * A.x;
                a3x += B.x * vx + B.y * vy + B.z * vz;
                a3y += B.y * vx + B.w * vy + Cc.x * vz;
                a3z += B.z * vx + Cc.x * vy + Cc.y * vz;
            }
        }
    }
    if (lane < 32) {
        M[wv][lane] = a0; M[wv][32 + lane] = a1x;
        M[wv][64 + lane] = a1y; M[wv][96 + lane] = a1z;
    } else if (lane < 48) {
        int m = lane - 32;
        M[wv][128 + m] = adv;
        M[wv][144 + m] = a2x; M[wv][160 + m] = a2y; M[wv][176 + m] = a2z;
        M[wv][192 + m] = a3x; M[wv][208 + m] = a3y; M[wv][224 + m] = a3z;
    }
    __syncthreads();
    if (act && lane < 32) {
        float ms = 0.f;
        for (int i = 0; i < 32; ++i) ms += M[wv][i] * w00[i * 32 + lane];
        for (int v = 0; v < 16; ++v) ms += M[wv][128 + v] * w110[v * 32 + lane];
        msbuf[n * 32 + lane] = ms;
    }
    if (act && lane < 48) {
        int c = lane >> 4, o = lane & 15;
        float mv = 0.f;
        for (int i = 0; i < 32; ++i) mv += M[wv][32 + c * 32 + i] * w01[i * 16 + o];
        for (int v = 0; v < 16; ++v) mv += M[wv][144 + c * 16 + v] * w10[v * 16 + o];
        for (int v = 0; v < 16; ++v) mv += M[wv][192 + c * 16 + v] * w12[v * 16 + o];
        mvbuf[n * 48 + lane] = mv;   // layout [c][o]
    }
}

// ---------------- per-layer node update (all cross-lane via LDS) -----------------------------
__global__ __launch_bounds__(256) void k_node(float* sbuf, float* vbuf,
        const float* msbuf, const float* mvbuf,
        const float* self_ws, const float* self_wv,
        const float* pre_ws, const float* pre_wv,
        const float* post_ws, const float* post_wv,
        const float* ln_g, const float* ln_b,
        const float* g_w1, const float* g_b1,
        const float* g_w2, const float* g_b2, int N) {
    __shared__ float S[4][32], V[4][48], P[4][48];
    int wv = threadIdx.x >> 6, lane = threadIdx.x & 63;
    int n = blockIdx.x * 4 + wv;
    bool act = n < N;
    int c = lane >> 4, o = lane & 15;

    if (act && lane < 32) S[wv][lane] = sbuf[n * 32 + lane];
    if (act && lane < 48) V[wv][lane] = vbuf[n * 48 + lane];
    __syncthreads();
    // s1 = s@self_ws + ms ; v1 = v.self_wv + mv
    float s1 = 0.f, v1 = 0.f;
    if (act && lane < 32) {
        s1 = msbuf[n * 32 + lane];
        for (int i = 0; i < 32; ++i) s1 += S[wv][i] * self_ws[i * 32 + lane];
    }
    if (act && lane < 48) {
        v1 = mvbuf[n * 48 + lane];
        for (int v = 0; v < 16; ++v) v1 += V[wv][c * 16 + v] * self_wv[v * 16 + o];
    }
    __syncthreads();
    if (lane < 32) S[wv][lane] = s1;
    if (lane < 48) V[wv][lane] = v1;
    __syncthreads();
    // ps = s1@pre_ws (48 wide) ; pv = v1.pre_wv
    float ps = 0.f, pv = 0.f;
    if (act && lane < 48) {
        for (int i = 0; i < 32; ++i) ps += S[wv][i] * pre_ws[i * 48 + lane];
        for (int v = 0; v < 16; ++v) pv += V[wv][c * 16 + v] * pre_wv[v * 16 + o];
    }
    if (lane < 48) P[wv][lane] = ps;
    __syncthreads();
    float g  = sigmoidf_(P[wv][32 + o]);
    float sc = (lane < 32) ? siluf(ps) : 0.f;
    float v2 = pv * g;
    __syncthreads();
    if (lane < 32) S[wv][lane] = sc;
    if (lane < 48) V[wv][lane] = v2;
    __syncthreads();
    // s2 = sc@post_ws ; v3 = v2.post_wv
    float s2 = 0.f, v3 = 0.f;
    if (act && lane < 32) { for (int i = 0; i < 32; ++i) s2 += S[wv][i] * post_ws[i * 32 + lane]; }
    if (act && lane < 48) { for (int v = 0; v < 16; ++v) v3 += V[wv][c * 16 + v] * post_wv[v * 16 + o]; }
    __syncthreads();
    if (lane < 32) S[wv][lane] = s2;
    if (lane < 48) V[wv][lane] = v3;
    __syncthreads();
    // LayerNorm over the 32 s-channels
    float sln = 0.f;
    if (act && lane < 32) {
        float mu = 0.f;
        for (int i = 0; i < 32; ++i) mu += S[wv][i];
        mu *= (1.0f / 32.0f);
        float var = 0.f;
        for (int i = 0; i < 32; ++i) { float t = S[wv][i] - mu; var += t * t; }
        var *= (1.0f / 32.0f);
        sln = (s2 - mu) * rsqrtf(var + 1e-5f) * ln_g[lane] + ln_b[lane];
    }
    // vn, gate MLP, delta
    if (lane < 16) {
        float vx = V[wv][lane], vy = V[wv][16 + lane], vz = V[wv][32 + lane];
        P[wv][lane] = sqrtf(vx * vx + vy * vy + vz * vz + 1e-12f);
    }
    __syncthreads();
    if (lane < 16) {
        float x = g_b1[lane];
        for (int m = 0; m < 16; ++m) x += P[wv][m] * g_w1[m * 16 + lane];
        P[wv][16 + lane] = siluf(x);
    }
    __syncthreads();
    if (act && lane < 32) {
        float dl = g_b2[lane];
        for (int oo = 0; oo < 16; ++oo) dl += P[wv][16 + oo] * g_w2[oo * 32 + lane];
        sbuf[n * 32 + lane] = sln + dl;
    }
    if (act && lane < 48) vbuf[n * 48 + lane] = v3;
}

// ---------------- final concat (f32 out) -----------------------------------------------------
__global__ void k_out(const float* sbuf, const float* vbuf, float* out, int N) {
    int idx = blockIdx.x * blockDim.x + threadIdx.x;
    if (idx >= N * 80) return;
    int n = idx / 80, j = idx - n * 80;
    float val;
    if (j < 32) val = sbuf[n * 32 + j];
    else {
        int jj = j - 32;
        int om = jj / 3, cc = jj - om * 3;
        val = vbuf[n * 48 + cc * 16 + om];
    }
    out[idx] = val;
}

extern "C" void kernel_launch(void* const* d_in, const int* in_sizes, int n_in,
                              void* d_out, int out_size, void* d_ws, size_t ws_size,
                              hipStream_t stream) {
    // inputs are float32 (established: round-1 bf16 decode NaN'd; round-2 f32 path was finite)
    auto F = [&](int i) { return (const float*)d_in[i]; };
    const int* z  = (const int*)d_in[31];
    const int* ei = (const int*)d_in[32];
    int N = in_sizes[0] / 3;
    int E = in_sizes[1];

    char* w = (char*)d_ws;
    size_t off = 0;
    auto take = [&](size_t bytes) { size_t cur = off; off += (bytes + 255) & ~(size_t)255; return cur; };
    float* attrs  = (float*)(w + take((size_t)E * 12 * 4));
    float* tab    = (float*)(w + take((size_t)TTAB * 40 * 4));
    int* cnt_dst  = (int*)(w + take((size_t)2 * N * 4));
    int* cnt_src  = cnt_dst + N;
    int* row_dst  = (int*)(w + take((size_t)(N + 1) * 4));
    int* row_src  = (int*)(w + take((size_t)(N + 1) * 4));
    int* cur_dst  = (int*)(w + take((size_t)N * 4));
    int* cur_src  = (int*)(w + take((size_t)N * 4));
    int* eid_dst  = (int*)(w + take((size_t)E * 4));
    int* eid_src  = (int*)(w + take((size_t)E * 4));
    float* sbuf   = (float*)(w + take((size_t)N * 32 * 4));
    float* vbuf   = (float*)(w + take((size_t)N * 48 * 4));
    float* msbuf  = (float*)(w + take((size_t)N * 32 * 4));
    float* mvbuf  = (float*)(w + take((size_t)N * 48 * 4));

    hipMemsetAsync(cnt_dst, 0, (size_t)2 * N * 4, stream);

    k_table<<<(TTAB + 255) / 256, 256, 0, stream>>>(F(8), F(9), F(10), F(11),
                                                    F(12), F(13), F(4), F(5), tab);
    k_edge<<<(E + 255) / 256, 256, 0, stream>>>(F(0), F(1), ei, tab, attrs,
                                                cnt_dst, cnt_src, E, N);
    k_scan<<<1, 1024, 0, stream>>>(cnt_dst, row_dst, cur_dst, N);
    k_scan<<<1, 1024, 0, stream>>>(cnt_src, row_src, cur_src, N);
    k_fill<<<(E + 255) / 256, 256, 0, stream>>>(ei, cur_dst, cur_src, eid_dst, eid_src, E);

    int nb = (N + 3) / 4;
    k_aggr<<<nb, 256, 0, stream>>>(row_src, eid_src, attrs, tab, ei, z,
                                   F(3), F(2), F(6), F(7), sbuf, vbuf, N, E);
    for (int li = 0; li < 4; ++li) {
        k_msg<<<nb, 256, 0, stream>>>(row_dst, eid_dst, ei, attrs, sbuf, vbuf,
                                      F(14) + li * 32 * 32, F(15) + li * 16 * 32,
                                      F(16) + li * 32 * 16, F(17) + li * 16 * 16,
                                      F(18) + li * 16 * 16, msbuf, mvbuf, N);
        k_node<<<nb, 256, 0, stream>>>(sbuf, vbuf, msbuf, mvbuf,
                                       F(19) + li * 32 * 32, F(20) + li * 16 * 16,
                                       F(21) + li * 32 * 48, F(22) + li * 16 * 16,
                                       F(23) + li * 32 * 32, F(24) + li * 16 * 16,
                                       F(25) + li * 32, F(26) + li * 32,
                                       F(27) + li * 16 * 16, F(28) + li * 16,
                                       F(29) + li * 16 * 32, F(30) + li * 32, N);
    }
    k_out<<<(N * 80 + 255) / 256, 256, 0, stream>>>(sbuf, vbuf, (float*)d_out, N);
}

// Round 4
// 1083.117 us; speedup vs baseline: 1.3519x; 1.3519x over previous
//
#include <hip/hip_runtime.h>

#define RCUT 3.5f
#define TTAB 2048

static __device__ __forceinline__ float sigmoidf_(float x) { return 1.0f / (1.0f + expf(-x)); }
static __device__ __forceinline__ float siluf(float x) { return x / (1.0f + expf(-x)); }
// nan_to_num: 0 for NaN/Inf (bit-pattern test, fast-math immune)
static __device__ __forceinline__ float san(float x) {
    return ((__float_as_uint(x) & 0x7F800000u) != 0x7F800000u) ? x : 0.f;
}

// ---------------- radial table: d -> [coeff0,coeff1,coeff2,pad, W0..31, pad4] (stride 40) ----
__global__ void k_table(const float* means, const float* betas,
                        const float* rad_w1, const float* rad_b1,
                        const float* rad_w2, const float* rad_b2,
                        const float* ne_dw, const float* ne_db,
                        float* tab) {
    int i = blockIdx.x * blockDim.x + threadIdx.x;
    if (i >= TTAB) return;
    float d  = (float)i * (RCUT / (float)(TTAB - 1));
    float dc = fmaxf(d, 1e-6f);
    float C  = (dc < RCUT) ? 0.5f * (cosf(dc * (3.14159265358979f / RCUT)) + 1.0f) : 0.0f;
    float ex = expf(-(5.0f / RCUT) * dc);
    float rbf[8];
#pragma unroll
    for (int nn = 0; nn < 8; ++nn) {
        float b = fmaxf(betas[nn], 1e-6f);
        float t = ex - means[nn];
        rbf[nn] = C * expf(-b * t * t);
    }
    for (int l = 0; l < 3; ++l) {
        float acc = rad_b2[l];
        for (int h = 0; h < 256; ++h) {
            float cc = rad_b1[l * 256 + h];
#pragma unroll
            for (int nn = 0; nn < 8; ++nn) cc += rbf[nn] * rad_w1[(l * 8 + nn) * 256 + h];
            acc += siluf(cc) * rad_w2[l * 256 + h];
        }
        tab[i * 40 + l] = acc;
    }
    tab[i * 40 + 3] = 0.f;
    for (int c = 0; c < 32; ++c) {
        float wv = ne_db[c];
#pragma unroll
        for (int nn = 0; nn < 8; ++nn) wv += rbf[nn] * ne_dw[nn * 32 + c];
        tab[i * 40 + 4 + c] = wv * C;   // W includes cutoff_fn(d)
    }
    tab[i * 40 + 36] = tab[i * 40 + 37] = tab[i * 40 + 38] = tab[i * 40 + 39] = 0.f;
}

// ---------------- per-edge attrs: [ae0, ae1x,ae1y,ae1z, q00,q01,q02,q11, q12,q22, d, 0] ------
__global__ void k_edge(const float* pos, const float* alpha,
                       const int* ei, const float* tab, float* attrs,
                       int* cnt_dst, int* cnt_src, int E, int N) {
    int e = blockIdx.x * blockDim.x + threadIdx.x;
    if (e >= E) return;
    int sn = ei[e], dn = ei[E + e];
    float rx = pos[dn * 3]     - pos[sn * 3];
    float ry = pos[dn * 3 + 1] - pos[sn * 3 + 1];
    float rz = pos[dn * 3 + 2] - pos[sn * 3 + 2];
    float d = sqrtf(rx * rx + ry * ry + rz * rz + 1e-12f);
    float inv = 1.0f / d;
    rx *= inv; ry *= inv; rz *= inv;
    float u = fminf(d, RCUT) * ((float)(TTAB - 1) / RCUT);
    int i0 = (int)u; if (i0 > TTAB - 2) i0 = TTAB - 2;
    float f = u - (float)i0;
    const float* t0 = tab + i0 * 40;
    float c0 = t0[0] + f * (t0[40] - t0[0]);
    float c1 = t0[1] + f * (t0[41] - t0[1]);
    float c2 = t0[2] + f * (t0[42] - t0[2]);
    float al = alpha[e];
    float ae0 = san(al * c0);
    float k1 = 1.73205081f * al * c1;      // sqrt(3)*alpha*coeff1
    float k2 = al * c2;
    float e20 = san(5.47722558f * rx * ry * k2);                             // sqrt(30) xy
    float e21 = san(5.47722558f * ry * rz * k2);
    float e22 = san(1.58113883f * (2.f * rz * rz - rx * rx - ry * ry) * k2); // sqrt(2.5)
    float e23 = san(5.47722558f * rx * rz * k2);
    float e24 = san(2.73861279f * (rx * rx - ry * ry) * k2);                 // sqrt(7.5)
    const float S2 = 0.70710678f, S6 = 0.40824829f;
    float q00 = -S6 * e22 + S2 * e24;
    float q01 = S2 * e20;
    float q02 = S2 * e23;
    float q11 = -S6 * e22 - S2 * e24;
    float q12 = S2 * e21;
    float q22 = 2.f * S6 * e22;
    float4* ap = (float4*)(attrs + (size_t)e * 12);
    ap[0] = make_float4(ae0, san(k1 * rx), san(k1 * ry), san(k1 * rz));
    ap[1] = make_float4(q00, q01, q02, q11);
    ap[2] = make_float4(q12, q22, d, 0.f);
    atomicAdd(cnt_dst + dn, 1);
    atomicAdd(cnt_src + sn, 1);
}

// ---------------- exclusive scan (single block, 1024 threads) --------------------------------
__global__ void k_scan(const int* __restrict__ cnt, int* __restrict__ rowptr,
                       int* __restrict__ cursor, int n) {
    __shared__ int lds[1024];
    __shared__ int carry_s;
    int tid = threadIdx.x;
    if (tid == 0) carry_s = 0;
    __syncthreads();
    int nch = (n + 1023) >> 10;
    for (int ch = 0; ch < nch; ++ch) {
        int idx = (ch << 10) + tid;
        int val = (idx < n) ? cnt[idx] : 0;
        lds[tid] = val;
        __syncthreads();
        for (int off = 1; off < 1024; off <<= 1) {
            int t = (tid >= off) ? lds[tid - off] : 0;
            __syncthreads();
            lds[tid] += t;
            __syncthreads();
        }
        int incl = lds[tid];
        int excl = incl - val;
        int base = carry_s;
        if (idx < n) { rowptr[idx] = base + excl; cursor[idx] = base + excl; }
        __syncthreads();
        if (tid == 1023) carry_s = base + incl;
        __syncthreads();
    }
    if (tid == 0) rowptr[n] = carry_s;
}

// ---------------- fill: build dst-sorted 48B records + src-sorted 8B aggr records ------------
// rec_dst slot layout: [ae0, ae1x, ae1y, ae1z, q00,q01,q02,q11, q12,q22, d, srcn(int)]
// rec_src: {u (table coord, clamped), z[dst]}
__global__ void k_fill(const int* ei, const float* attrs, const int* z,
                       int* cur_dst, int* cur_src, float* rec_dst, int2* rec_src, int E) {
    int e = blockIdx.x * blockDim.x + threadIdx.x;
    if (e >= E) return;
    int sn = ei[e], dn = ei[E + e];
    const float4* ap = (const float4*)(attrs + (size_t)e * 12);
    float4 a = ap[0], b = ap[1], c = ap[2];
    int p = atomicAdd(cur_dst + dn, 1);
    float d = c.z;
    c.w = __int_as_float(sn);
    float4* rp = (float4*)(rec_dst + (size_t)p * 12);
    rp[0] = a; rp[1] = b; rp[2] = c;
    int p2 = atomicAdd(cur_src + sn, 1);
    float u = fminf(fminf(d, RCUT) * ((float)(TTAB - 1) / RCUT), (float)(TTAB - 1) - 1e-3f);
    rec_src[p2] = make_int2(__float_as_int(u), z[dn]);
}

// ---------------- aggr (src-sorted records) + initial node embed; v layout [c][m] ------------
__global__ __launch_bounds__(256) void k_aggr(const int* row_src, const int2* recs,
        const int* z, const float* tab, const float* ne_emb, const float* atom_emb,
        const float* ne_cw, const float* ne_cb,
        float* sbuf, float* vbuf, int N) {
    __shared__ float part[4][64];
    __shared__ float cat[4][64];
    int wv = threadIdx.x >> 6, lane = threadIdx.x & 63;
    int n = blockIdx.x * 4 + wv;
    bool act = n < N;
    int g = lane >> 5, li = lane & 31;
    float acc = 0.f;
    if (act) {
        int r0 = row_src[n], r1 = row_src[n + 1];
        int half = (r1 - r0) >> 1;
        int kb = g ? (r0 + half) : r0;
        int ke = g ? r1 : (r0 + half);
        int k = kb;
        for (; k + 2 <= ke; k += 2) {
            int2 rA = recs[k], rB = recs[k + 1];
            float uA = __int_as_float(rA.x), uB = __int_as_float(rB.x);
            int iA = (int)uA, iB = (int)uB;
            float fA = uA - (float)iA, fB = uB - (float)iB;
            float wA0 = tab[iA * 40 + 4 + li], wA1 = tab[iA * 40 + 44 + li];
            float wB0 = tab[iB * 40 + 4 + li], wB1 = tab[iB * 40 + 44 + li];
            float eA = ne_emb[rA.y * 32 + li], eB = ne_emb[rB.y * 32 + li];
            acc += (wA0 + fA * (wA1 - wA0)) * eA + (wB0 + fB * (wB1 - wB0)) * eB;
        }
        for (; k < ke; ++k) {
            int2 r = recs[k];
            float u = __int_as_float(r.x);
            int i0 = (int)u; float f = u - (float)i0;
            float w0 = tab[i0 * 40 + 4 + li], w1 = tab[i0 * 40 + 44 + li];
            acc += (w0 + f * (w1 - w0)) * ne_emb[r.y * 32 + li];
        }
    }
    part[wv][lane] = acc;
    __syncthreads();
    if (act && lane < 32) {
        cat[wv][lane] = atom_emb[z[n] * 32 + lane];
        cat[wv][32 + lane] = part[wv][lane] + part[wv][32 + lane];
    }
    __syncthreads();
    if (act && lane < 32) {
        float so = ne_cb[lane];
        for (int j = 0; j < 64; ++j) so += cat[wv][j] * ne_cw[j * 32 + lane];
        sbuf[n * 32 + lane] = so;
    }
    if (act && lane < 48) vbuf[n * 48 + lane] = 0.f;
}

// ---------------- per-layer message kernel (dst-sorted records, 4x batched gathers) ----------
// LDS layout per wave: [0:32) a0 | [32:128) a1(c*32+i) | [128:144) adv
//                      [144:192) a2(c*16+m) | [192:240) a3(c*16+m)
__global__ __launch_bounds__(256) void k_msg(const int* row_dst, const float* recs,
        const float* sbuf, const float* vbuf,
        const float* w00, const float* w110, const float* w01,
        const float* w10, const float* w12,
        float* msbuf, float* mvbuf, int N) {
    __shared__ float M[4][240];
    int wv = threadIdx.x >> 6, lane = threadIdx.x & 63;
    int n = blockIdx.x * 4 + wv;
    bool act = n < N;
    float a0 = 0.f, a1x = 0.f, a1y = 0.f, a1z = 0.f;
    float adv = 0.f, a2x = 0.f, a2y = 0.f, a2z = 0.f, a3x = 0.f, a3y = 0.f, a3z = 0.f;
    if (act && lane < 48) {
        int r0 = row_dst[n], r1 = row_dst[n + 1];
        int vv = lane - 32;
        int k = r0;
        for (; k + 4 <= r1; k += 4) {
            const float* rb = recs + (size_t)k * 12;
            float4 A0 = *(const float4*)(rb);
            float4 A1 = *(const float4*)(rb + 12);
            float4 A2 = *(const float4*)(rb + 24);
            float4 A3 = *(const float4*)(rb + 36);
            int s0 = __float_as_int(rb[11]);
            int s1 = __float_as_int(rb[23]);
            int s2 = __float_as_int(rb[35]);
            int s3 = __float_as_int(rb[47]);
            if (lane < 32) {
                float x0 = sbuf[s0 * 32 + lane];
                float x1 = sbuf[s1 * 32 + lane];
                float x2 = sbuf[s2 * 32 + lane];
                float x3 = sbuf[s3 * 32 + lane];
                a0  += x0 * A0.x + x1 * A1.x + x2 * A2.x + x3 * A3.x;
                a1x += x0 * A0.y + x1 * A1.y + x2 * A2.y + x3 * A3.y;
                a1y += x0 * A0.z + x1 * A1.z + x2 * A2.z + x3 * A3.z;
                a1z += x0 * A0.w + x1 * A1.w + x2 * A2.w + x3 * A3.w;
            } else {
                float4 B0 = *(const float4*)(rb + 4);
                float4 B1 = *(const float4*)(rb + 16);
                float4 Bb2 = *(const float4*)(rb + 28);
                float4 B3 = *(const float4*)(rb + 40);
                float2 C0 = *(const float2*)(rb + 8);
                float2 C1 = *(const float2*)(rb + 20);
                float2 C2 = *(const float2*)(rb + 32);
                float2 C3 = *(const float2*)(rb + 44);
                const float* vp0 = vbuf + (size_t)s0 * 48;
                const float* vp1 = vbuf + (size_t)s1 * 48;
                const float* vp2 = vbuf + (size_t)s2 * 48;
                const float* vp3 = vbuf + (size_t)s3 * 48;
                float vx0 = vp0[vv], vy0 = vp0[16 + vv], vz0 = vp0[32 + vv];
                float vx1 = vp1[vv], vy1 = vp1[16 + vv], vz1 = vp1[32 + vv];
                float vx2 = vp2[vv], vy2 = vp2[16 + vv], vz2 = vp2[32 + vv];
                float vx3 = vp3[vv], vy3 = vp3[16 + vv], vz3 = vp3[32 + vv];
                adv += vx0*A0.y + vy0*A0.z + vz0*A0.w + vx1*A1.y + vy1*A1.z + vz1*A1.w
                     + vx2*A2.y + vy2*A2.z + vz2*A2.w + vx3*A3.y + vy3*A3.z + vz3*A3.w;
                a2x += vx0*A0.x + vx1*A1.x + vx2*A2.x + vx3*A3.x;
                a2y += vy0*A0.x + vy1*A1.x + vy2*A2.x + vy3*A3.x;
                a2z += vz0*A0.x + vz1*A1.x + vz2*A2.x + vz3*A3.x;
                a3x += B0.x*vx0 + B0.y*vy0 + B0.z*vz0 + B1.x*vx1 + B1.y*vy1 + B1.z*vz1
                     + Bb2.x*vx2 + Bb2.y*vy2 + Bb2.z*vz2 + B3.x*vx3 + B3.y*vy3 + B3.z*vz3;
                a3y += B0.y*vx0 + B0.w*vy0 + C0.x*vz0 + B1.y*vx1 + B1.w*vy1 + C1.x*vz1
                     + Bb2.y*vx2 + Bb2.w*vy2 + C2.x*vz2 + B3.y*vx3 + B3.w*vy3 + C3.x*vz3;
                a3z += B0.z*vx0 + C0.x*vy0 + C0.y*vz0 + B1.z*vx1 + C1.x*vy1 + C1.y*vz1
                     + Bb2.z*vx2 + C2.x*vy2 + C2.y*vz2 + B3.z*vx3 + C3.x*vy3 + C3.y*vz3;
            }
        }
        for (; k < r1; ++k) {
            const float* rb = recs + (size_t)k * 12;
            float4 A = *(const float4*)(rb);
            int sn = __float_as_int(rb[11]);
            if (lane < 32) {
                float ssi = sbuf[sn * 32 + lane];
                a0 += ssi * A.x; a1x += ssi * A.y; a1y += ssi * A.z; a1z += ssi * A.w;
            } else {
                float4 B = *(const float4*)(rb + 4);
                float2 Cc = *(const float2*)(rb + 8);
                const float* vp = vbuf + (size_t)sn * 48;
                float vx = vp[vv], vy = vp[16 + vv], vz = vp[32 + vv];
                adv += vx * A.y + vy * A.z + vz * A.w;
                a2x += vx * A.x; a2y += vy * A.x; a2z += vz * A.x;
                a3x += B.x * vx + B.y * vy + B.z * vz;
                a3y += B.y * vx + B.w * vy + Cc.x * vz;
                a3z += B.z * vx + Cc.x * vy + Cc.y * vz;
            }
        }
    }
    if (lane < 32) {
        M[wv][lane] = a0; M[wv][32 + lane] = a1x;
        M[wv][64 + lane] = a1y; M[wv][96 + lane] = a1z;
    } else if (lane < 48) {
        int m = lane - 32;
        M[wv][128 + m] = adv;
        M[wv][144 + m] = a2x; M[wv][160 + m] = a2y; M[wv][176 + m] = a2z;
        M[wv][192 + m] = a3x; M[wv][208 + m] = a3y; M[wv][224 + m] = a3z;
    }
    __syncthreads();
    if (act && lane < 32) {
        float ms = 0.f;
        for (int i = 0; i < 32; ++i) ms += M[wv][i] * w00[i * 32 + lane];
        for (int v = 0; v < 16; ++v) ms += M[wv][128 + v] * w110[v * 32 + lane];
        msbuf[n * 32 + lane] = ms;
    }
    if (act && lane < 48) {
        int c = lane >> 4, o = lane & 15;
        float mv = 0.f;
        for (int i = 0; i < 32; ++i) mv += M[wv][32 + c * 32 + i] * w01[i * 16 + o];
        for (int v = 0; v < 16; ++v) mv += M[wv][144 + c * 16 + v] * w10[v * 16 + o];
        for (int v = 0; v < 16; ++v) mv += M[wv][192 + c * 16 + v] * w12[v * 16 + o];
        mvbuf[n * 48 + lane] = mv;   // layout [c][o]
    }
}

// ---------------- per-layer node update (all cross-lane via LDS) -----------------------------
__global__ __launch_bounds__(256) void k_node(float* sbuf, float* vbuf,
        const float* msbuf, const float* mvbuf,
        const float* self_ws, const float* self_wv,
        const float* pre_ws, const float* pre_wv,
        const float* post_ws, const float* post_wv,
        const float* ln_g, const float* ln_b,
        const float* g_w1, const float* g_b1,
        const float* g_w2, const float* g_b2, int N) {
    __shared__ float S[4][32], V[4][48], P[4][48];
    int wv = threadIdx.x >> 6, lane = threadIdx.x & 63;
    int n = blockIdx.x * 4 + wv;
    bool act = n < N;
    int c = lane >> 4, o = lane & 15;

    if (act && lane < 32) S[wv][lane] = sbuf[n * 32 + lane];
    if (act && lane < 48) V[wv][lane] = vbuf[n * 48 + lane];
    __syncthreads();
    float s1 = 0.f, v1 = 0.f;
    if (act && lane < 32) {
        s1 = msbuf[n * 32 + lane];
        for (int i = 0; i < 32; ++i) s1 += S[wv][i] * self_ws[i * 32 + lane];
    }
    if (act && lane < 48) {
        v1 = mvbuf[n * 48 + lane];
        for (int v = 0; v < 16; ++v) v1 += V[wv][c * 16 + v] * self_wv[v * 16 + o];
    }
    __syncthreads();
    if (lane < 32) S[wv][lane] = s1;
    if (lane < 48) V[wv][lane] = v1;
    __syncthreads();
    float ps = 0.f, pv = 0.f;
    if (act && lane < 48) {
        for (int i = 0; i < 32; ++i) ps += S[wv][i] * pre_ws[i * 48 + lane];
        for (int v = 0; v < 16; ++v) pv += V[wv][c * 16 + v] * pre_wv[v * 16 + o];
    }
    if (lane < 48) P[wv][lane] = ps;
    __syncthreads();
    float g  = sigmoidf_(P[wv][32 + o]);
    float sc = (lane < 32) ? siluf(ps) : 0.f;
    float v2 = pv * g;
    __syncthreads();
    if (lane < 32) S[wv][lane] = sc;
    if (lane < 48) V[wv][lane] = v2;
    __syncthreads();
    float s2 = 0.f, v3 = 0.f;
    if (act && lane < 32) { for (int i = 0; i < 32; ++i) s2 += S[wv][i] * post_ws[i * 32 + lane]; }
    if (act && lane < 48) { for (int v = 0; v < 16; ++v) v3 += V[wv][c * 16 + v] * post_wv[v * 16 + o]; }
    __syncthreads();
    if (lane < 32) S[wv][lane] = s2;
    if (lane < 48) V[wv][lane] = v3;
    __syncthreads();
    float sln = 0.f;
    if (act && lane < 32) {
        float mu = 0.f;
        for (int i = 0; i < 32; ++i) mu += S[wv][i];
        mu *= (1.0f / 32.0f);
        float var = 0.f;
        for (int i = 0; i < 32; ++i) { float t = S[wv][i] - mu; var += t * t; }
        var *= (1.0f / 32.0f);
        sln = (s2 - mu) * rsqrtf(var + 1e-5f) * ln_g[lane] + ln_b[lane];
    }
    if (lane < 16) {
        float vx = V[wv][lane], vy = V[wv][16 + lane], vz = V[wv][32 + lane];
        P[wv][lane] = sqrtf(vx * vx + vy * vy + vz * vz + 1e-12f);
    }
    __syncthreads();
    if (lane < 16) {
        float x = g_b1[lane];
        for (int m = 0; m < 16; ++m) x += P[wv][m] * g_w1[m * 16 + lane];
        P[wv][16 + lane] = siluf(x);
    }
    __syncthreads();
    if (act && lane < 32) {
        float dl = g_b2[lane];
        for (int oo = 0; oo < 16; ++oo) dl += P[wv][16 + oo] * g_w2[oo * 32 + lane];
        sbuf[n * 32 + lane] = sln + dl;
    }
    if (act && lane < 48) vbuf[n * 48 + lane] = v3;
}

// ---------------- final concat (f32 out) -----------------------------------------------------
__global__ void k_out(const float* sbuf, const float* vbuf, float* out, int N) {
    int idx = blockIdx.x * blockDim.x + threadIdx.x;
    if (idx >= N * 80) return;
    int n = idx / 80, j = idx - n * 80;
    float val;
    if (j < 32) val = sbuf[n * 32 + j];
    else {
        int jj = j - 32;
        int om = jj / 3, cc = jj - om * 3;
        val = vbuf[n * 48 + cc * 16 + om];
    }
    out[idx] = val;
}

extern "C" void kernel_launch(void* const* d_in, const int* in_sizes, int n_in,
                              void* d_out, int out_size, void* d_ws, size_t ws_size,
                              hipStream_t stream) {
    auto F = [&](int i) { return (const float*)d_in[i]; };
    const int* z  = (const int*)d_in[31];
    const int* ei = (const int*)d_in[32];
    int N = in_sizes[0] / 3;
    int E = in_sizes[1];

    char* w = (char*)d_ws;
    size_t off = 0;
    auto take = [&](size_t bytes) { size_t cur = off; off += (bytes + 255) & ~(size_t)255; return cur; };
    float* attrs   = (float*)(w + take((size_t)E * 12 * 4));
    float* rec_dst = (float*)(w + take((size_t)E * 12 * 4));
    int2*  rec_src = (int2*)(w + take((size_t)E * 8));
    float* tab     = (float*)(w + take((size_t)TTAB * 40 * 4));
    int* cnt_dst   = (int*)(w + take((size_t)2 * N * 4));
    int* cnt_src   = cnt_dst + N;
    int* row_dst   = (int*)(w + take((size_t)(N + 1) * 4));
    int* row_src   = (int*)(w + take((size_t)(N + 1) * 4));
    int* cur_dst   = (int*)(w + take((size_t)N * 4));
    int* cur_src   = (int*)(w + take((size_t)N * 4));
    float* sbuf    = (float*)(w + take((size_t)N * 32 * 4));
    float* vbuf    = (float*)(w + take((size_t)N * 48 * 4));
    float* msbuf   = (float*)(w + take((size_t)N * 32 * 4));
    float* mvbuf   = (float*)(w + take((size_t)N * 48 * 4));

    hipMemsetAsync(cnt_dst, 0, (size_t)2 * N * 4, stream);

    k_table<<<(TTAB + 255) / 256, 256, 0, stream>>>(F(8), F(9), F(10), F(11),
                                                    F(12), F(13), F(4), F(5), tab);
    k_edge<<<(E + 255) / 256, 256, 0, stream>>>(F(0), F(1), ei, tab, attrs,
                                                cnt_dst, cnt_src, E, N);
    k_scan<<<1, 1024, 0, stream>>>(cnt_dst, row_dst, cur_dst, N);
    k_scan<<<1, 1024, 0, stream>>>(cnt_src, row_src, cur_src, N);
    k_fill<<<(E + 255) / 256, 256, 0, stream>>>(ei, attrs, z, cur_dst, cur_src,
                                                rec_dst, rec_src, E);

    int nb = (N + 3) / 4;
    k_aggr<<<nb, 256, 0, stream>>>(row_src, rec_src, z, tab, F(3), F(2),
                                   F(6), F(7), sbuf, vbuf, N);
    for (int li = 0; li < 4; ++li) {
        k_msg<<<nb, 256, 0, stream>>>(row_dst, rec_dst, sbuf, vbuf,
                                      F(14) + li * 32 * 32, F(15) + li * 16 * 32,
                                      F(16) + li * 32 * 16, F(17) + li * 16 * 16,
                                      F(18) + li * 16 * 16, msbuf, mvbuf, N);
        k_node<<<nb, 256, 0, stream>>>(sbuf, vbuf, msbuf, mvbuf,
                                       F(19) + li * 32 * 32, F(20) + li * 16 * 16,
                                       F(21) + li * 32 * 48, F(22) + li * 16 * 16,
                                       F(23) + li * 32 * 32, F(24) + li * 16 * 16,
                                       F(25) + li * 32, F(26) + li * 32,
                                       F(27) + li * 16 * 16, F(28) + li * 16,
                                       F(29) + li * 16 * 32, F(30) + li * 32, N);
    }
    k_out<<<(N * 80 + 255) / 256, 256, 0, stream>>>(sbuf, vbuf, (float*)d_out, N);
}

// Round 5
// 911.825 us; speedup vs baseline: 1.6059x; 1.1879x over previous
//
#include <hip/hip_runtime.h>

#define RCUT 3.5f
#define TTAB 2048

static __device__ __forceinline__ float sigmoidf_(float x) { return 1.0f / (1.0f + expf(-x)); }
static __device__ __forceinline__ float siluf(float x) { return x / (1.0f + expf(-x)); }
// nan_to_num: 0 for NaN/Inf (bit-pattern test, fast-math immune)
static __device__ __forceinline__ float san(float x) {
    return ((__float_as_uint(x) & 0x7F800000u) != 0x7F800000u) ? x : 0.f;
}

// ---------------- radial table: block per entry, thread per hidden unit ----------------------
// tab entry i (stride 40): [coeff0,coeff1,coeff2,pad, W0..31, pad4]
__global__ __launch_bounds__(256) void k_table(const float* means, const float* betas,
                        const float* rad_w1, const float* rad_b1,
                        const float* rad_w2, const float* rad_b2,
                        const float* ne_dw, const float* ne_db,
                        float* tab) {
    __shared__ float red[3][4];
    int i = blockIdx.x;
    int h = threadIdx.x;
    int lane = h & 63, wv = h >> 6;
    float d  = (float)i * (RCUT / (float)(TTAB - 1));
    float dc = fmaxf(d, 1e-6f);
    float C  = (dc < RCUT) ? 0.5f * (cosf(dc * (3.14159265358979f / RCUT)) + 1.0f) : 0.0f;
    float ex = expf(-(5.0f / RCUT) * dc);
    float rbf[8];
#pragma unroll
    for (int nn = 0; nn < 8; ++nn) {
        float b = fmaxf(betas[nn], 1e-6f);
        float t = ex - means[nn];
        rbf[nn] = C * expf(-b * t * t);
    }
    float con[3];
#pragma unroll
    for (int l = 0; l < 3; ++l) {
        float cc = rad_b1[l * 256 + h];
#pragma unroll
        for (int nn = 0; nn < 8; ++nn) cc += rbf[nn] * rad_w1[(l * 8 + nn) * 256 + h];
        con[l] = siluf(cc) * rad_w2[l * 256 + h];
    }
#pragma unroll
    for (int m = 1; m < 64; m <<= 1) {
        con[0] += __shfl_xor(con[0], m, 64);
        con[1] += __shfl_xor(con[1], m, 64);
        con[2] += __shfl_xor(con[2], m, 64);
    }
    if (lane == 0) { red[0][wv] = con[0]; red[1][wv] = con[1]; red[2][wv] = con[2]; }
    __syncthreads();
    if (h < 3)
        tab[i * 40 + h] = rad_b2[h] + red[h][0] + red[h][1] + red[h][2] + red[h][3];
    else if (h == 3)
        tab[i * 40 + 3] = 0.f;
    else if (h < 36) {
        int c = h - 4;
        float wvv = ne_db[c];
#pragma unroll
        for (int nn = 0; nn < 8; ++nn) wvv += rbf[nn] * ne_dw[nn * 32 + c];
        tab[i * 40 + h] = wvv * C;   // W includes cutoff_fn(d)
    } else if (h < 40)
        tab[i * 40 + h] = 0.f;
}

// ---------------- per-edge attrs: [ae0, ae1x,ae1y,ae1z, q00,q01,q02,q11, q12,q22, d, 0] ------
__global__ void k_edge(const float* pos, const float* alpha,
                       const int* ei, const float* tab, float* attrs,
                       int* cnt_dst, int* cnt_src, int E, int N) {
    int e = blockIdx.x * blockDim.x + threadIdx.x;
    if (e >= E) return;
    int sn = ei[e], dn = ei[E + e];
    float rx = pos[dn * 3]     - pos[sn * 3];
    float ry = pos[dn * 3 + 1] - pos[sn * 3 + 1];
    float rz = pos[dn * 3 + 2] - pos[sn * 3 + 2];
    float d = sqrtf(rx * rx + ry * ry + rz * rz + 1e-12f);
    float inv = 1.0f / d;
    rx *= inv; ry *= inv; rz *= inv;
    float u = fminf(d, RCUT) * ((float)(TTAB - 1) / RCUT);
    int i0 = (int)u; if (i0 > TTAB - 2) i0 = TTAB - 2;
    float f = u - (float)i0;
    const float* t0 = tab + i0 * 40;
    float c0 = t0[0] + f * (t0[40] - t0[0]);
    float c1 = t0[1] + f * (t0[41] - t0[1]);
    float c2 = t0[2] + f * (t0[42] - t0[2]);
    float al = alpha[e];
    float ae0 = san(al * c0);
    float k1 = 1.73205081f * al * c1;      // sqrt(3)*alpha*coeff1
    float k2 = al * c2;
    float e20 = san(5.47722558f * rx * ry * k2);                             // sqrt(30) xy
    float e21 = san(5.47722558f * ry * rz * k2);
    float e22 = san(1.58113883f * (2.f * rz * rz - rx * rx - ry * ry) * k2); // sqrt(2.5)
    float e23 = san(5.47722558f * rx * rz * k2);
    float e24 = san(2.73861279f * (rx * rx - ry * ry) * k2);                 // sqrt(7.5)
    const float S2 = 0.70710678f, S6 = 0.40824829f;
    float q00 = -S6 * e22 + S2 * e24;
    float q01 = S2 * e20;
    float q02 = S2 * e23;
    float q11 = -S6 * e22 - S2 * e24;
    float q12 = S2 * e21;
    float q22 = 2.f * S6 * e22;
    float4* ap = (float4*)(attrs + (size_t)e * 12);
    ap[0] = make_float4(ae0, san(k1 * rx), san(k1 * ry), san(k1 * rz));
    ap[1] = make_float4(q00, q01, q02, q11);
    ap[2] = make_float4(q12, q22, d, 0.f);
    atomicAdd(cnt_dst + dn, 1);
    atomicAdd(cnt_src + sn, 1);
}

// ---------------- dual exclusive scan (2 blocks, wave-scan based) ----------------------------
__global__ void k_scan2(const int* cntA, int* rowA, int* curA,
                        const int* cntB, int* rowB, int* curB, int n) {
    __shared__ int wtot[16];
    __shared__ int carry_s;
    const int* cnt = blockIdx.x ? cntB : cntA;
    int* rowptr    = blockIdx.x ? rowB : rowA;
    int* cursor    = blockIdx.x ? curB : curA;
    int tid = threadIdx.x, lane = tid & 63, wv = tid >> 6;
    if (tid == 0) carry_s = 0;
    __syncthreads();
    int nch = (n + 1023) >> 10;
    for (int ch = 0; ch < nch; ++ch) {
        int idx = (ch << 10) + tid;
        int val = (idx < n) ? cnt[idx] : 0;
        int v = val;
#pragma unroll
        for (int m = 1; m < 64; m <<= 1) {
            int t = __shfl_up(v, m, 64);
            if (lane >= m) v += t;
        }
        if (lane == 63) wtot[wv] = v;
        __syncthreads();
        int wbase = 0;
        for (int j = 0; j < wv; ++j) wbase += wtot[j];
        int base = carry_s;
        int incl = v + wbase;
        int excl = incl - val;
        if (idx < n) { rowptr[idx] = base + excl; cursor[idx] = base + excl; }
        __syncthreads();
        if (tid == 1023) carry_s = base + incl;
        __syncthreads();
    }
    if (tid == 0) rowptr[n] = carry_s;
}

// ---------------- fill: build dst-sorted 48B records + src-sorted 8B aggr records ------------
// rec_dst slot layout: [ae0, ae1x, ae1y, ae1z, q00,q01,q02,q11, q12,q22, d, srcn(int)]
// rec_src: {u (table coord, clamped), z[dst]}
__global__ void k_fill(const int* ei, const float* attrs, const int* z,
                       int* cur_dst, int* cur_src, float* rec_dst, int2* rec_src, int E) {
    int e = blockIdx.x * blockDim.x + threadIdx.x;
    if (e >= E) return;
    int sn = ei[e], dn = ei[E + e];
    const float4* ap = (const float4*)(attrs + (size_t)e * 12);
    float4 a = ap[0], b = ap[1], c = ap[2];
    int p = atomicAdd(cur_dst + dn, 1);
    float d = c.z;
    c.w = __int_as_float(sn);
    float4* rp = (float4*)(rec_dst + (size_t)p * 12);
    rp[0] = a; rp[1] = b; rp[2] = c;
    int p2 = atomicAdd(cur_src + sn, 1);
    float u = fminf(fminf(d, RCUT) * ((float)(TTAB - 1) / RCUT), (float)(TTAB - 1) - 1e-3f);
    rec_src[p2] = make_int2(__float_as_int(u), z[dn]);
}

// ---------------- aggr (src-sorted records) + initial node embed; v layout [c][m] ------------
__global__ __launch_bounds__(256) void k_aggr(const int* row_src, const int2* recs,
        const int* z, const float* tab, const float* ne_emb, const float* atom_emb,
        const float* ne_cw, const float* ne_cb,
        float* sbuf, float* vbuf, int N) {
    __shared__ float part[4][64];
    __shared__ float cat[4][64];
    int wv = threadIdx.x >> 6, lane = threadIdx.x & 63;
    int n = blockIdx.x * 4 + wv;
    bool act = n < N;
    int g = lane >> 5, li = lane & 31;
    float acc = 0.f;
    if (act) {
        int r0 = row_src[n], r1 = row_src[n + 1];
        int half = (r1 - r0) >> 1;
        int kb = g ? (r0 + half) : r0;
        int ke = g ? r1 : (r0 + half);
        int k = kb;
        for (; k + 2 <= ke; k += 2) {
            int2 rA = recs[k], rB = recs[k + 1];
            float uA = __int_as_float(rA.x), uB = __int_as_float(rB.x);
            int iA = (int)uA, iB = (int)uB;
            float fA = uA - (float)iA, fB = uB - (float)iB;
            float wA0 = tab[iA * 40 + 4 + li], wA1 = tab[iA * 40 + 44 + li];
            float wB0 = tab[iB * 40 + 4 + li], wB1 = tab[iB * 40 + 44 + li];
            float eA = ne_emb[rA.y * 32 + li], eB = ne_emb[rB.y * 32 + li];
            acc += (wA0 + fA * (wA1 - wA0)) * eA + (wB0 + fB * (wB1 - wB0)) * eB;
        }
        for (; k < ke; ++k) {
            int2 r = recs[k];
            float u = __int_as_float(r.x);
            int i0 = (int)u; float f = u - (float)i0;
            float w0 = tab[i0 * 40 + 4 + li], w1 = tab[i0 * 40 + 44 + li];
            acc += (w0 + f * (w1 - w0)) * ne_emb[r.y * 32 + li];
        }
    }
    part[wv][lane] = acc;
    __syncthreads();
    if (act && lane < 32) {
        cat[wv][lane] = atom_emb[z[n] * 32 + lane];
        cat[wv][32 + lane] = part[wv][lane] + part[wv][32 + lane];
    }
    __syncthreads();
    if (act && lane < 32) {
        float so = ne_cb[lane];
        for (int j = 0; j < 64; ++j) so += cat[wv][j] * ne_cw[j * 32 + lane];
        sbuf[n * 32 + lane] = so;
    }
    if (act && lane < 48) vbuf[n * 48 + lane] = 0.f;
}

// ---------------- per-layer message kernel (dst-sorted records, 4x batched gathers) ----------
// LDS layout per wave: [0:32) a0 | [32:128) a1(c*32+i) | [128:144) adv
//                      [144:192) a2(c*16+m) | [192:240) a3(c*16+m)
__global__ __launch_bounds__(256) void k_msg(const int* row_dst, const float* recs,
        const float* sbuf, const float* vbuf,
        const float* w00, const float* w110, const float* w01,
        const float* w10, const float* w12,
        float* msbuf, float* mvbuf, int N) {
    __shared__ float M[4][240];
    int wv = threadIdx.x >> 6, lane = threadIdx.x & 63;
    int n = blockIdx.x * 4 + wv;
    bool act = n < N;
    float a0 = 0.f, a1x = 0.f, a1y = 0.f, a1z = 0.f;
    float adv = 0.f, a2x = 0.f, a2y = 0.f, a2z = 0.f, a3x = 0.f, a3y = 0.f, a3z = 0.f;
    if (act && lane < 48) {
        int r0 = row_dst[n], r1 = row_dst[n + 1];
        int vv = lane - 32;
        int k = r0;
        for (; k + 4 <= r1; k += 4) {
            const float* rb = recs + (size_t)k * 12;
            float4 A0 = *(const float4*)(rb);
            float4 A1 = *(const float4*)(rb + 12);
            float4 A2 = *(const float4*)(rb + 24);
            float4 A3 = *(const float4*)(rb + 36);
            int s0 = __float_as_int(rb[11]);
            int s1 = __float_as_int(rb[23]);
            int s2 = __float_as_int(rb[35]);
            int s3 = __float_as_int(rb[47]);
            if (lane < 32) {
                float x0 = sbuf[s0 * 32 + lane];
                float x1 = sbuf[s1 * 32 + lane];
                float x2 = sbuf[s2 * 32 + lane];
                float x3 = sbuf[s3 * 32 + lane];
                a0  += x0 * A0.x + x1 * A1.x + x2 * A2.x + x3 * A3.x;
                a1x += x0 * A0.y + x1 * A1.y + x2 * A2.y + x3 * A3.y;
                a1y += x0 * A0.z + x1 * A1.z + x2 * A2.z + x3 * A3.z;
                a1z += x0 * A0.w + x1 * A1.w + x2 * A2.w + x3 * A3.w;
            } else {
                float4 B0 = *(const float4*)(rb + 4);
                float4 B1 = *(const float4*)(rb + 16);
                float4 Bb2 = *(const float4*)(rb + 28);
                float4 B3 = *(const float4*)(rb + 40);
                float2 C0 = *(const float2*)(rb + 8);
                float2 C1 = *(const float2*)(rb + 20);
                float2 C2 = *(const float2*)(rb + 32);
                float2 C3 = *(const float2*)(rb + 44);
                const float* vp0 = vbuf + (size_t)s0 * 48;
                const float* vp1 = vbuf + (size_t)s1 * 48;
                const float* vp2 = vbuf + (size_t)s2 * 48;
                const float* vp3 = vbuf + (size_t)s3 * 48;
                float vx0 = vp0[vv], vy0 = vp0[16 + vv], vz0 = vp0[32 + vv];
                float vx1 = vp1[vv], vy1 = vp1[16 + vv], vz1 = vp1[32 + vv];
                float vx2 = vp2[vv], vy2 = vp2[16 + vv], vz2 = vp2[32 + vv];
                float vx3 = vp3[vv], vy3 = vp3[16 + vv], vz3 = vp3[32 + vv];
                adv += vx0*A0.y + vy0*A0.z + vz0*A0.w + vx1*A1.y + vy1*A1.z + vz1*A1.w
                     + vx2*A2.y + vy2*A2.z + vz2*A2.w + vx3*A3.y + vy3*A3.z + vz3*A3.w;
                a2x += vx0*A0.x + vx1*A1.x + vx2*A2.x + vx3*A3.x;
                a2y += vy0*A0.x + vy1*A1.x + vy2*A2.x + vy3*A3.x;
                a2z += vz0*A0.x + vz1*A1.x + vz2*A2.x + vz3*A3.x;
                a3x += B0.x*vx0 + B0.y*vy0 + B0.z*vz0 + B1.x*vx1 + B1.y*vy1 + B1.z*vz1
                     + Bb2.x*vx2 + Bb2.y*vy2 + Bb2.z*vz2 + B3.x*vx3 + B3.y*vy3 + B3.z*vz3;
                a3y += B0.y*vx0 + B0.w*vy0 + C0.x*vz0 + B1.y*vx1 + B1.w*vy1 + C1.x*vz1
                     + Bb2.y*vx2 + Bb2.w*vy2 + C2.x*vz2 + B3.y*vx3 + B3.w*vy3 + C3.x*vz3;
                a3z += B0.z*vx0 + C0.x*vy0 + C0.y*vz0 + B1.z*vx1 + C1.x*vy1 + C1.y*vz1
                     + Bb2.z*vx2 + C2.x*vy2 + C2.y*vz2 + B3.z*vx3 + C3.x*vy3 + C3.y*vz3;
            }
        }
        for (; k < r1; ++k) {
            const float* rb = recs + (size_t)k * 12;
            float4 A = *(const float4*)(rb);
            int sn = __float_as_int(rb[11]);
            if (lane < 32) {
                float ssi = sbuf[sn * 32 + lane];
                a0 += ssi * A.x; a1x += ssi * A.y; a1y += ssi * A.z; a1z += ssi * A.w;
            } else {
                float4 B = *(const float4*)(rb + 4);
                float2 Cc = *(const float2*)(rb + 8);
                const float* vp = vbuf + (size_t)sn * 48;
                float vx = vp[vv], vy = vp[16 + vv], vz = vp[32 + vv];
                adv += vx * A.y + vy * A.z + vz * A.w;
                a2x += vx * A.x; a2y += vy * A.x; a2z += vz * A.x;
                a3x += B.x * vx + B.y * vy + B.z * vz;
                a3y += B.y * vx + B.w * vy + Cc.x * vz;
                a3z += B.z * vx + Cc.x * vy + Cc.y * vz;
            }
        }
    }
    if (lane < 32) {
        M[wv][lane] = a0; M[wv][32 + lane] = a1x;
        M[wv][64 + lane] = a1y; M[wv][96 + lane] = a1z;
    } else if (lane < 48) {
        int m = lane - 32;
        M[wv][128 + m] = adv;
        M[wv][144 + m] = a2x; M[wv][160 + m] = a2y; M[wv][176 + m] = a2z;
        M[wv][192 + m] = a3x; M[wv][208 + m] = a3y; M[wv][224 + m] = a3z;
    }
    __syncthreads();
    if (act && lane < 32) {
        float ms = 0.f;
        for (int i = 0; i < 32; ++i) ms += M[wv][i] * w00[i * 32 + lane];
        for (int v = 0; v < 16; ++v) ms += M[wv][128 + v] * w110[v * 32 + lane];
        msbuf[n * 32 + lane] = ms;
    }
    if (act && lane < 48) {
        int c = lane >> 4, o = lane & 15;
        float mv = 0.f;
        for (int i = 0; i < 32; ++i) mv += M[wv][32 + c * 32 + i] * w01[i * 16 + o];
        for (int v = 0; v < 16; ++v) mv += M[wv][144 + c * 16 + v] * w10[v * 16 + o];
        for (int v = 0; v < 16; ++v) mv += M[wv][192 + c * 16 + v] * w12[v * 16 + o];
        mvbuf[n * 48 + lane] = mv;   // layout [c][o]
    }
}

// ---------------- per-layer node update (all cross-lane via LDS) -----------------------------
__global__ __launch_bounds__(256) void k_node(float* sbuf, float* vbuf,
        const float* msbuf, const float* mvbuf,
        const float* self_ws, const float* self_wv,
        const float* pre_ws, const float* pre_wv,
        const float* post_ws, const float* post_wv,
        const float* ln_g, const float* ln_b,
        const float* g_w1, const float* g_b1,
        const float* g_w2, const float* g_b2, int N) {
    __shared__ float S[4][32], V[4][48], P[4][48];
    int wv = threadIdx.x >> 6, lane = threadIdx.x & 63;
    int n = blockIdx.x * 4 + wv;
    bool act = n < N;
    int c = lane >> 4, o = lane & 15;

    if (act && lane < 32) S[wv][lane] = sbuf[n * 32 + lane];
    if (act && lane < 48) V[wv][lane] = vbuf[n * 48 + lane];
    __syncthreads();
    float s1 = 0.f, v1 = 0.f;
    if (act && lane < 32) {
        s1 = msbuf[n * 32 + lane];
        for (int i = 0; i < 32; ++i) s1 += S[wv][i] * self_ws[i * 32 + lane];
    }
    if (act && lane < 48) {
        v1 = mvbuf[n * 48 + lane];
        for (int v = 0; v < 16; ++v) v1 += V[wv][c * 16 + v] * self_wv[v * 16 + o];
    }
    __syncthreads();
    if (lane < 32) S[wv][lane] = s1;
    if (lane < 48) V[wv][lane] = v1;
    __syncthreads();
    float ps = 0.f, pv = 0.f;
    if (act && lane < 48) {
        for (int i = 0; i < 32; ++i) ps += S[wv][i] * pre_ws[i * 48 + lane];
        for (int v = 0; v < 16; ++v) pv += V[wv][c * 16 + v] * pre_wv[v * 16 + o];
    }
    if (lane < 48) P[wv][lane] = ps;
    __syncthreads();
    float g  = sigmoidf_(P[wv][32 + o]);
    float sc = (lane < 32) ? siluf(ps) : 0.f;
    float v2 = pv * g;
    __syncthreads();
    if (lane < 32) S[wv][lane] = sc;
    if (lane < 48) V[wv][lane] = v2;
    __syncthreads();
    float s2 = 0.f, v3 = 0.f;
    if (act && lane < 32) { for (int i = 0; i < 32; ++i) s2 += S[wv][i] * post_ws[i * 32 + lane]; }
    if (act && lane < 48) { for (int v = 0; v < 16; ++v) v3 += V[wv][c * 16 + v] * post_wv[v * 16 + o]; }
    __syncthreads();
    if (lane < 32) S[wv][lane] = s2;
    if (lane < 48) V[wv][lane] = v3;
    __syncthreads();
    float sln = 0.f;
    if (act && lane < 32) {
        float mu = 0.f;
        for (int i = 0; i < 32; ++i) mu += S[wv][i];
        mu *= (1.0f / 32.0f);
        float var = 0.f;
        for (int i = 0; i < 32; ++i) { float t = S[wv][i] - mu; var += t * t; }
        var *= (1.0f / 32.0f);
        sln = (s2 - mu) * rsqrtf(var + 1e-5f) * ln_g[lane] + ln_b[lane];
    }
    if (lane < 16) {
        float vx = V[wv][lane], vy = V[wv][16 + lane], vz = V[wv][32 + lane];
        P[wv][lane] = sqrtf(vx * vx + vy * vy + vz * vz + 1e-12f);
    }
    __syncthreads();
    if (lane < 16) {
        float x = g_b1[lane];
        for (int m = 0; m < 16; ++m) x += P[wv][m] * g_w1[m * 16 + lane];
        P[wv][16 + lane] = siluf(x);
    }
    __syncthreads();
    if (act && lane < 32) {
        float dl = g_b2[lane];
        for (int oo = 0; oo < 16; ++oo) dl += P[wv][16 + oo] * g_w2[oo * 32 + lane];
        sbuf[n * 32 + lane] = sln + dl;
    }
    if (act && lane < 48) vbuf[n * 48 + lane] = v3;
}

// ---------------- final concat (f32 out) -----------------------------------------------------
__global__ void k_out(const float* sbuf, const float* vbuf, float* out, int N) {
    int idx = blockIdx.x * blockDim.x + threadIdx.x;
    if (idx >= N * 80) return;
    int n = idx / 80, j = idx - n * 80;
    float val;
    if (j < 32) val = sbuf[n * 32 + j];
    else {
        int jj = j - 32;
        int om = jj / 3, cc = jj - om * 3;
        val = vbuf[n * 48 + cc * 16 + om];
    }
    out[idx] = val;
}

extern "C" void kernel_launch(void* const* d_in, const int* in_sizes, int n_in,
                              void* d_out, int out_size, void* d_ws, size_t ws_size,
                              hipStream_t stream) {
    auto F = [&](int i) { return (const float*)d_in[i]; };
    const int* z  = (const int*)d_in[31];
    const int* ei = (const int*)d_in[32];
    int N = in_sizes[0] / 3;
    int E = in_sizes[1];

    char* w = (char*)d_ws;
    size_t off = 0;
    auto take = [&](size_t bytes) { size_t cur = off; off += (bytes + 255) & ~(size_t)255; return cur; };
    float* attrs   = (float*)(w + take((size_t)E * 12 * 4));
    float* rec_dst = (float*)(w + take((size_t)E * 12 * 4));
    int2*  rec_src = (int2*)(w + take((size_t)E * 8));
    float* tab     = (float*)(w + take((size_t)TTAB * 40 * 4));
    int* cnt_dst   = (int*)(w + take((size_t)2 * N * 4));
    int* cnt_src   = cnt_dst + N;
    int* row_dst   = (int*)(w + take((size_t)(N + 1) * 4));
    int* row_src   = (int*)(w + take((size_t)(N + 1) * 4));
    int* cur_dst   = (int*)(w + take((size_t)N * 4));
    int* cur_src   = (int*)(w + take((size_t)N * 4));
    float* sbuf    = (float*)(w + take((size_t)N * 32 * 4));
    float* vbuf    = (float*)(w + take((size_t)N * 48 * 4));
    float* msbuf   = (float*)(w + take((size_t)N * 32 * 4));
    float* mvbuf   = (float*)(w + take((size_t)N * 48 * 4));

    hipMemsetAsync(cnt_dst, 0, (size_t)2 * N * 4, stream);

    k_table<<<TTAB, 256, 0, stream>>>(F(8), F(9), F(10), F(11),
                                      F(12), F(13), F(4), F(5), tab);
    k_edge<<<(E + 255) / 256, 256, 0, stream>>>(F(0), F(1), ei, tab, attrs,
                                                cnt_dst, cnt_src, E, N);
    k_scan2<<<2, 1024, 0, stream>>>(cnt_dst, row_dst, cur_dst,
                                    cnt_src, row_src, cur_src, N);
    k_fill<<<(E + 255) / 256, 256, 0, stream>>>(ei, attrs, z, cur_dst, cur_src,
                                                rec_dst, rec_src, E);

    int nb = (N + 3) / 4;
    k_aggr<<<nb, 256, 0, stream>>>(row_src, rec_src, z, tab, F(3), F(2),
                                   F(6), F(7), sbuf, vbuf, N);
    for (int li = 0; li < 4; ++li) {
        k_msg<<<nb, 256, 0, stream>>>(row_dst, rec_dst, sbuf, vbuf,
                                      F(14) + li * 32 * 32, F(15) + li * 16 * 32,
                                      F(16) + li * 32 * 16, F(17) + li * 16 * 16,
                                      F(18) + li * 16 * 16, msbuf, mvbuf, N);
        k_node<<<nb, 256, 0, stream>>>(sbuf, vbuf, msbuf, mvbuf,
                                       F(19) + li * 32 * 32, F(20) + li * 16 * 16,
                                       F(21) + li * 32 * 48, F(22) + li * 16 * 16,
                                       F(23) + li * 32 * 32, F(24) + li * 16 * 16,
                                       F(25) + li * 32, F(26) + li * 32,
                                       F(27) + li * 16 * 16, F(28) + li * 16,
                                       F(29) + li * 16 * 32, F(30) + li * 32, N);
    }
    k_out<<<(N * 80 + 255) / 256, 256, 0, stream>>>(sbuf, vbuf, (float*)d_out, N);
}

// Round 6
// 821.047 us; speedup vs baseline: 1.7834x; 1.1106x over previous
//
#include <hip/hip_runtime.h>

#define RCUT 3.5f
#define TTAB 2048

static __device__ __forceinline__ float sigmoidf_(float x) { return 1.0f / (1.0f + expf(-x)); }
static __device__ __forceinline__ float siluf(float x) { return x / (1.0f + expf(-x)); }
// nan_to_num: 0 for NaN/Inf (bit-pattern test, fast-math immune)
static __device__ __forceinline__ float san(float x) {
    return ((__float_as_uint(x) & 0x7F800000u) != 0x7F800000u) ? x : 0.f;
}

// ---------------- radial table: block per entry, thread per hidden unit ----------------------
// tab entry i (stride 40): [coeff0,coeff1,coeff2,pad, W0..31, pad4]
__global__ __launch_bounds__(256) void k_table(const float* means, const float* betas,
                        const float* rad_w1, const float* rad_b1,
                        const float* rad_w2, const float* rad_b2,
                        const float* ne_dw, const float* ne_db,
                        float* tab) {
    __shared__ float red[3][4];
    int i = blockIdx.x;
    int h = threadIdx.x;
    int lane = h & 63, wv = h >> 6;
    float d  = (float)i * (RCUT / (float)(TTAB - 1));
    float dc = fmaxf(d, 1e-6f);
    float C  = (dc < RCUT) ? 0.5f * (cosf(dc * (3.14159265358979f / RCUT)) + 1.0f) : 0.0f;
    float ex = expf(-(5.0f / RCUT) * dc);
    float rbf[8];
#pragma unroll
    for (int nn = 0; nn < 8; ++nn) {
        float b = fmaxf(betas[nn], 1e-6f);
        float t = ex - means[nn];
        rbf[nn] = C * expf(-b * t * t);
    }
    float con[3];
#pragma unroll
    for (int l = 0; l < 3; ++l) {
        float cc = rad_b1[l * 256 + h];
#pragma unroll
        for (int nn = 0; nn < 8; ++nn) cc += rbf[nn] * rad_w1[(l * 8 + nn) * 256 + h];
        con[l] = siluf(cc) * rad_w2[l * 256 + h];
    }
#pragma unroll
    for (int m = 1; m < 64; m <<= 1) {
        con[0] += __shfl_xor(con[0], m, 64);
        con[1] += __shfl_xor(con[1], m, 64);
        con[2] += __shfl_xor(con[2], m, 64);
    }
    if (lane == 0) { red[0][wv] = con[0]; red[1][wv] = con[1]; red[2][wv] = con[2]; }
    __syncthreads();
    if (h < 3)
        tab[i * 40 + h] = rad_b2[h] + red[h][0] + red[h][1] + red[h][2] + red[h][3];
    else if (h == 3)
        tab[i * 40 + 3] = 0.f;
    else if (h < 36) {
        int c = h - 4;
        float wvv = ne_db[c];
#pragma unroll
        for (int nn = 0; nn < 8; ++nn) wvv += rbf[nn] * ne_dw[nn * 32 + c];
        tab[i * 40 + h] = wvv * C;   // W includes cutoff_fn(d)
    } else if (h < 40)
        tab[i * 40 + h] = 0.f;
}

// ---------------- count degrees ---------------------------------------------------------------
__global__ void k_count(const int* ei, int* cnt_dst, int* cnt_src, int E) {
    int e = blockIdx.x * blockDim.x + threadIdx.x;
    if (e >= E) return;
    atomicAdd(cnt_dst + ei[E + e], 1);
    atomicAdd(cnt_src + ei[e], 1);
}

// ---------------- dual exclusive scan (2 blocks, wave-scan based) ----------------------------
__global__ void k_scan2(const int* cntA, int* rowA, int* curA,
                        const int* cntB, int* rowB, int* curB, int n) {
    __shared__ int wtot[16];
    __shared__ int carry_s;
    const int* cnt = blockIdx.x ? cntB : cntA;
    int* rowptr    = blockIdx.x ? rowB : rowA;
    int* cursor    = blockIdx.x ? curB : curA;
    int tid = threadIdx.x, lane = tid & 63, wv = tid >> 6;
    if (tid == 0) carry_s = 0;
    __syncthreads();
    int nch = (n + 1023) >> 10;
    for (int ch = 0; ch < nch; ++ch) {
        int idx = (ch << 10) + tid;
        int val = (idx < n) ? cnt[idx] : 0;
        int v = val;
#pragma unroll
        for (int m = 1; m < 64; m <<= 1) {
            int t = __shfl_up(v, m, 64);
            if (lane >= m) v += t;
        }
        if (lane == 63) wtot[wv] = v;
        __syncthreads();
        int wbase = 0;
        for (int j = 0; j < wv; ++j) wbase += wtot[j];
        int base = carry_s;
        int incl = v + wbase;
        int excl = incl - val;
        if (idx < n) { rowptr[idx] = base + excl; cursor[idx] = base + excl; }
        __syncthreads();
        if (tid == 1023) carry_s = base + incl;
        __syncthreads();
    }
    if (tid == 0) rowptr[n] = carry_s;
}

// ---------------- fused edge-compute + scatter to dst-sorted records -------------------------
// rec_dst slot (stride 12 floats): [ae0, ae1x, ae1y, ae1z, q00,q01,q02,q11, q12,q22, 0,0]
// col_dst: srcn per slot. rec_src: {u (table coord, clamped), z[dst]}
__global__ void k_edge_fill(const float* pos, const float* alpha,
                            const int* ei, const float* tab, const int* z,
                            int* cur_dst, int* cur_src,
                            float* rec_dst, int* col_dst, int2* rec_src, int E) {
    int e = blockIdx.x * blockDim.x + threadIdx.x;
    if (e >= E) return;
    int sn = ei[e], dn = ei[E + e];
    float rx = pos[dn * 3]     - pos[sn * 3];
    float ry = pos[dn * 3 + 1] - pos[sn * 3 + 1];
    float rz = pos[dn * 3 + 2] - pos[sn * 3 + 2];
    float d = sqrtf(rx * rx + ry * ry + rz * rz + 1e-12f);
    float inv = 1.0f / d;
    rx *= inv; ry *= inv; rz *= inv;
    float u = fminf(d, RCUT) * ((float)(TTAB - 1) / RCUT);
    int i0 = (int)u; if (i0 > TTAB - 2) i0 = TTAB - 2;
    float f = u - (float)i0;
    const float* t0 = tab + i0 * 40;
    float c0 = t0[0] + f * (t0[40] - t0[0]);
    float c1 = t0[1] + f * (t0[41] - t0[1]);
    float c2 = t0[2] + f * (t0[42] - t0[2]);
    float al = alpha[e];
    float ae0 = san(al * c0);
    float k1 = 1.73205081f * al * c1;      // sqrt(3)*alpha*coeff1
    float k2 = al * c2;
    float e20 = san(5.47722558f * rx * ry * k2);                             // sqrt(30) xy
    float e21 = san(5.47722558f * ry * rz * k2);
    float e22 = san(1.58113883f * (2.f * rz * rz - rx * rx - ry * ry) * k2); // sqrt(2.5)
    float e23 = san(5.47722558f * rx * rz * k2);
    float e24 = san(2.73861279f * (rx * rx - ry * ry) * k2);                 // sqrt(7.5)
    const float S2 = 0.70710678f, S6 = 0.40824829f;
    float q00 = -S6 * e22 + S2 * e24;
    float q01 = S2 * e20;
    float q02 = S2 * e23;
    float q11 = -S6 * e22 - S2 * e24;
    float q12 = S2 * e21;
    float q22 = 2.f * S6 * e22;
    int p = atomicAdd(cur_dst + dn, 1);
    float4* rp = (float4*)(rec_dst + (size_t)p * 12);
    rp[0] = make_float4(ae0, san(k1 * rx), san(k1 * ry), san(k1 * rz));
    rp[1] = make_float4(q00, q01, q02, q11);
    rp[2] = make_float4(q12, q22, 0.f, 0.f);
    col_dst[p] = sn;
    int p2 = atomicAdd(cur_src + sn, 1);
    float uc = fminf(u, (float)(TTAB - 1) - 1e-3f);
    rec_src[p2] = make_int2(__float_as_int(uc), z[dn]);
}

// ---------------- aggr (src-sorted records) + initial node embed; v layout [c][m] ------------
__global__ __launch_bounds__(256) void k_aggr(const int* row_src, const int2* recs,
        const int* z, const float* tab, const float* ne_emb, const float* atom_emb,
        const float* ne_cw, const float* ne_cb,
        float* sbuf, float* vbuf, int N) {
    __shared__ float part[4][64];
    __shared__ float cat[4][64];
    int wv = threadIdx.x >> 6, lane = threadIdx.x & 63;
    int n = blockIdx.x * 4 + wv;
    bool act = n < N;
    int g = lane >> 5, li = lane & 31;
    float acc = 0.f;
    if (act) {
        int r0 = row_src[n], r1 = row_src[n + 1];
        int half = (r1 - r0) >> 1;
        int kb = g ? (r0 + half) : r0;
        int ke = g ? r1 : (r0 + half);
        int k = kb;
        for (; k + 2 <= ke; k += 2) {
            int2 rA = recs[k], rB = recs[k + 1];
            float uA = __int_as_float(rA.x), uB = __int_as_float(rB.x);
            int iA = (int)uA, iB = (int)uB;
            float fA = uA - (float)iA, fB = uB - (float)iB;
            float wA0 = tab[iA * 40 + 4 + li], wA1 = tab[iA * 40 + 44 + li];
            float wB0 = tab[iB * 40 + 4 + li], wB1 = tab[iB * 40 + 44 + li];
            float eA = ne_emb[rA.y * 32 + li], eB = ne_emb[rB.y * 32 + li];
            acc += (wA0 + fA * (wA1 - wA0)) * eA + (wB0 + fB * (wB1 - wB0)) * eB;
        }
        for (; k < ke; ++k) {
            int2 r = recs[k];
            float u = __int_as_float(r.x);
            int i0 = (int)u; float f = u - (float)i0;
            float w0 = tab[i0 * 40 + 4 + li], w1 = tab[i0 * 40 + 44 + li];
            acc += (w0 + f * (w1 - w0)) * ne_emb[r.y * 32 + li];
        }
    }
    part[wv][lane] = acc;
    __syncthreads();
    if (act && lane < 32) {
        cat[wv][lane] = atom_emb[z[n] * 32 + lane];
        cat[wv][32 + lane] = part[wv][lane] + part[wv][32 + lane];
    }
    __syncthreads();
    if (act && lane < 32) {
        float so = ne_cb[lane];
        for (int j = 0; j < 64; ++j) so += cat[wv][j] * ne_cw[j * 32 + lane];
        sbuf[n * 32 + lane] = so;
    }
    if (act && lane < 48) vbuf[n * 48 + lane] = 0.f;
}

// ---------------- per-layer message kernel -----------------------------------------------------
// col prefetched one iter ahead (breaks record->gather chain); v-side split over 2x16 lanes.
// LDS per wave (352 floats): [0:32) a0 | [32:128) a1(c*32+i)
//   group g base = 128+g*112: [+0:16) adv | [+16:64) a2(c*16+m) | [+64:112) a3(c*16+m)
__global__ __launch_bounds__(256) void k_msg(const int* row_dst, const float* recs,
        const int* col, const float* sbuf, const float* vbuf,
        const float* w00, const float* w110, const float* w01,
        const float* w10, const float* w12,
        float* msbuf, float* mvbuf, int N) {
    __shared__ float M[4][352];
    int wv = threadIdx.x >> 6, lane = threadIdx.x & 63;
    int n = blockIdx.x * 4 + wv;
    bool act = n < N;
    float a0 = 0.f, a1x = 0.f, a1y = 0.f, a1z = 0.f;
    float adv = 0.f, a2x = 0.f, a2y = 0.f, a2z = 0.f, a3x = 0.f, a3y = 0.f, a3z = 0.f;
    int r0 = 0, r1 = 0;
    if (act) { r0 = row_dst[n]; r1 = row_dst[n + 1]; }
    int s0 = 0, s1 = 0, s2 = 0, s3 = 0;
    if (r0 + 4 <= r1) { s0 = col[r0]; s1 = col[r0 + 1]; s2 = col[r0 + 2]; s3 = col[r0 + 3]; }
    int k = r0;
    for (; k + 4 <= r1; k += 4) {
        int c0 = s0, c1 = s1, c2 = s2, c3 = s3;
        if (k + 8 <= r1) { s0 = col[k + 4]; s1 = col[k + 5]; s2 = col[k + 6]; s3 = col[k + 7]; }
        const float* rb = recs + (size_t)k * 12;
        if (lane < 32) {
            float4 A0 = *(const float4*)(rb);
            float4 A1 = *(const float4*)(rb + 12);
            float4 A2 = *(const float4*)(rb + 24);
            float4 A3 = *(const float4*)(rb + 36);
            float x0 = sbuf[c0 * 32 + lane];
            float x1 = sbuf[c1 * 32 + lane];
            float x2 = sbuf[c2 * 32 + lane];
            float x3 = sbuf[c3 * 32 + lane];
            a0  += x0 * A0.x + x1 * A1.x + x2 * A2.x + x3 * A3.x;
            a1x += x0 * A0.y + x1 * A1.y + x2 * A2.y + x3 * A3.y;
            a1y += x0 * A0.z + x1 * A1.z + x2 * A2.z + x3 * A3.z;
            a1z += x0 * A0.w + x1 * A1.w + x2 * A2.w + x3 * A3.w;
        } else {
            int g = (lane >> 4) & 1, m = lane & 15;
            const float* rbA = rb + g * 24;     // edges k+2g, k+2g+1
            float4 Aa = *(const float4*)(rbA);
            float4 Ba = *(const float4*)(rbA + 4);
            float2 Ca = *(const float2*)(rbA + 8);
            float4 Ab = *(const float4*)(rbA + 12);
            float4 Bb = *(const float4*)(rbA + 16);
            float2 Cb = *(const float2*)(rbA + 20);
            int sA = g ? c2 : c0, sB = g ? c3 : c1;
            const float* vpA = vbuf + (size_t)sA * 48;
            const float* vpB = vbuf + (size_t)sB * 48;
            float vxA = vpA[m], vyA = vpA[16 + m], vzA = vpA[32 + m];
            float vxB = vpB[m], vyB = vpB[16 + m], vzB = vpB[32 + m];
            adv += vxA*Aa.y + vyA*Aa.z + vzA*Aa.w + vxB*Ab.y + vyB*Ab.z + vzB*Ab.w;
            a2x += vxA*Aa.x + vxB*Ab.x;
            a2y += vyA*Aa.x + vyB*Ab.x;
            a2z += vzA*Aa.x + vzB*Ab.x;
            a3x += Ba.x*vxA + Ba.y*vyA + Ba.z*vzA + Bb.x*vxB + Bb.y*vyB + Bb.z*vzB;
            a3y += Ba.y*vxA + Ba.w*vyA + Ca.x*vzA + Bb.y*vxB + Bb.w*vyB + Cb.x*vzB;
            a3z += Ba.z*vxA + Ca.x*vyA + Ca.y*vzA + Bb.z*vxB + Cb.x*vyB + Cb.y*vzB;
        }
    }
    for (; k < r1; ++k) {                      // tail: lanes 32..47 only on v-side
        const float* rb = recs + (size_t)k * 12;
        int sn = col[k];
        if (lane < 32) {
            float4 A = *(const float4*)(rb);
            float ssi = sbuf[sn * 32 + lane];
            a0 += ssi * A.x; a1x += ssi * A.y; a1y += ssi * A.z; a1z += ssi * A.w;
        } else if (lane < 48) {
            float4 A = *(const float4*)(rb);
            float4 B = *(const float4*)(rb + 4);
            float2 Cc = *(const float2*)(rb + 8);
            int vvm = lane - 32;
            const float* vp = vbuf + (size_t)sn * 48;
            float vx = vp[vvm], vy = vp[16 + vvm], vz = vp[32 + vvm];
            adv += vx * A.y + vy * A.z + vz * A.w;
            a2x += vx * A.x; a2y += vy * A.x; a2z += vz * A.x;
            a3x += B.x * vx + B.y * vy + B.z * vz;
            a3y += B.y * vx + B.w * vy + Cc.x * vz;
            a3z += B.z * vx + Cc.x * vy + Cc.y * vz;
        }
    }
    if (lane < 32) {
        M[wv][lane] = a0; M[wv][32 + lane] = a1x;
        M[wv][64 + lane] = a1y; M[wv][96 + lane] = a1z;
    } else {
        int g = (lane >> 4) & 1, m = lane & 15;
        int base = 128 + g * 112;
        M[wv][base + m] = adv;
        M[wv][base + 16 + m] = a2x; M[wv][base + 32 + m] = a2y; M[wv][base + 48 + m] = a2z;
        M[wv][base + 64 + m] = a3x; M[wv][base + 80 + m] = a3y; M[wv][base + 96 + m] = a3z;
    }
    __syncthreads();
    if (act && lane < 32) {
        float ms = 0.f;
        for (int i = 0; i < 32; ++i) ms += M[wv][i] * w00[i * 32 + lane];
        for (int v = 0; v < 16; ++v)
            ms += (M[wv][128 + v] + M[wv][240 + v]) * w110[v * 32 + lane];
        msbuf[n * 32 + lane] = ms;
    }
    if (act && lane < 48) {
        int c = lane >> 4, o = lane & 15;
        float mv = 0.f;
        for (int i = 0; i < 32; ++i) mv += M[wv][32 + c * 32 + i] * w01[i * 16 + o];
        for (int v = 0; v < 16; ++v)
            mv += (M[wv][144 + c * 16 + v] + M[wv][256 + c * 16 + v]) * w10[v * 16 + o];
        for (int v = 0; v < 16; ++v)
            mv += (M[wv][192 + c * 16 + v] + M[wv][304 + c * 16 + v]) * w12[v * 16 + o];
        mvbuf[n * 48 + lane] = mv;   // layout [c][o]
    }
}

// ---------------- per-layer node update (all cross-lane via LDS) -----------------------------
__global__ __launch_bounds__(256) void k_node(float* sbuf, float* vbuf,
        const float* msbuf, const float* mvbuf,
        const float* self_ws, const float* self_wv,
        const float* pre_ws, const float* pre_wv,
        const float* post_ws, const float* post_wv,
        const float* ln_g, const float* ln_b,
        const float* g_w1, const float* g_b1,
        const float* g_w2, const float* g_b2, int N) {
    __shared__ float S[4][32], V[4][48], P[4][48];
    int wv = threadIdx.x >> 6, lane = threadIdx.x & 63;
    int n = blockIdx.x * 4 + wv;
    bool act = n < N;
    int c = lane >> 4, o = lane & 15;

    if (act && lane < 32) S[wv][lane] = sbuf[n * 32 + lane];
    if (act && lane < 48) V[wv][lane] = vbuf[n * 48 + lane];
    __syncthreads();
    float s1 = 0.f, v1 = 0.f;
    if (act && lane < 32) {
        s1 = msbuf[n * 32 + lane];
        for (int i = 0; i < 32; ++i) s1 += S[wv][i] * self_ws[i * 32 + lane];
    }
    if (act && lane < 48) {
        v1 = mvbuf[n * 48 + lane];
        for (int v = 0; v < 16; ++v) v1 += V[wv][c * 16 + v] * self_wv[v * 16 + o];
    }
    __syncthreads();
    if (lane < 32) S[wv][lane] = s1;
    if (lane < 48) V[wv][lane] = v1;
    __syncthreads();
    float ps = 0.f, pv = 0.f;
    if (act && lane < 48) {
        for (int i = 0; i < 32; ++i) ps += S[wv][i] * pre_ws[i * 48 + lane];
        for (int v = 0; v < 16; ++v) pv += V[wv][c * 16 + v] * pre_wv[v * 16 + o];
    }
    if (lane < 48) P[wv][lane] = ps;
    __syncthreads();
    float g  = sigmoidf_(P[wv][32 + o]);
    float sc = (lane < 32) ? siluf(ps) : 0.f;
    float v2 = pv * g;
    __syncthreads();
    if (lane < 32) S[wv][lane] = sc;
    if (lane < 48) V[wv][lane] = v2;
    __syncthreads();
    float s2 = 0.f, v3 = 0.f;
    if (act && lane < 32) { for (int i = 0; i < 32; ++i) s2 += S[wv][i] * post_ws[i * 32 + lane]; }
    if (act && lane < 48) { for (int v = 0; v < 16; ++v) v3 += V[wv][c * 16 + v] * post_wv[v * 16 + o]; }
    __syncthreads();
    if (lane < 32) S[wv][lane] = s2;
    if (lane < 48) V[wv][lane] = v3;
    __syncthreads();
    float sln = 0.f;
    if (act && lane < 32) {
        float mu = 0.f;
        for (int i = 0; i < 32; ++i) mu += S[wv][i];
        mu *= (1.0f / 32.0f);
        float var = 0.f;
        for (int i = 0; i < 32; ++i) { float t = S[wv][i] - mu; var += t * t; }
        var *= (1.0f / 32.0f);
        sln = (s2 - mu) * rsqrtf(var + 1e-5f) * ln_g[lane] + ln_b[lane];
    }
    if (lane < 16) {
        float vx = V[wv][lane], vy = V[wv][16 + lane], vz = V[wv][32 + lane];
        P[wv][lane] = sqrtf(vx * vx + vy * vy + vz * vz + 1e-12f);
    }
    __syncthreads();
    if (lane < 16) {
        float x = g_b1[lane];
        for (int m = 0; m < 16; ++m) x += P[wv][m] * g_w1[m * 16 + lane];
        P[wv][16 + lane] = siluf(x);
    }
    __syncthreads();
    if (act && lane < 32) {
        float dl = g_b2[lane];
        for (int oo = 0; oo < 16; ++oo) dl += P[wv][16 + oo] * g_w2[oo * 32 + lane];
        sbuf[n * 32 + lane] = sln + dl;
    }
    if (act && lane < 48) vbuf[n * 48 + lane] = v3;
}

// ---------------- final concat (f32 out) -----------------------------------------------------
__global__ void k_out(const float* sbuf, const float* vbuf, float* out, int N) {
    int idx = blockIdx.x * blockDim.x + threadIdx.x;
    if (idx >= N * 80) return;
    int n = idx / 80, j = idx - n * 80;
    float val;
    if (j < 32) val = sbuf[n * 32 + j];
    else {
        int jj = j - 32;
        int om = jj / 3, cc = jj - om * 3;
        val = vbuf[n * 48 + cc * 16 + om];
    }
    out[idx] = val;
}

extern "C" void kernel_launch(void* const* d_in, const int* in_sizes, int n_in,
                              void* d_out, int out_size, void* d_ws, size_t ws_size,
                              hipStream_t stream) {
    auto F = [&](int i) { return (const float*)d_in[i]; };
    const int* z  = (const int*)d_in[31];
    const int* ei = (const int*)d_in[32];
    int N = in_sizes[0] / 3;
    int E = in_sizes[1];

    char* w = (char*)d_ws;
    size_t off = 0;
    auto take = [&](size_t bytes) { size_t cur = off; off += (bytes + 255) & ~(size_t)255; return cur; };
    float* rec_dst = (float*)(w + take((size_t)E * 12 * 4));
    int*   col_dst = (int*)(w + take((size_t)E * 4));
    int2*  rec_src = (int2*)(w + take((size_t)E * 8));
    float* tab     = (float*)(w + take((size_t)TTAB * 40 * 4));
    int* cnt_dst   = (int*)(w + take((size_t)2 * N * 4));
    int* cnt_src   = cnt_dst + N;
    int* row_dst   = (int*)(w + take((size_t)(N + 1) * 4));
    int* row_src   = (int*)(w + take((size_t)(N + 1) * 4));
    int* cur_dst   = (int*)(w + take((size_t)N * 4));
    int* cur_src   = (int*)(w + take((size_t)N * 4));
    float* sbuf    = (float*)(w + take((size_t)N * 32 * 4));
    float* vbuf    = (float*)(w + take((size_t)N * 48 * 4));
    float* msbuf   = (float*)(w + take((size_t)N * 32 * 4));
    float* mvbuf   = (float*)(w + take((size_t)N * 48 * 4));

    hipMemsetAsync(cnt_dst, 0, (size_t)2 * N * 4, stream);

    k_table<<<TTAB, 256, 0, stream>>>(F(8), F(9), F(10), F(11),
                                      F(12), F(13), F(4), F(5), tab);
    k_count<<<(E + 255) / 256, 256, 0, stream>>>(ei, cnt_dst, cnt_src, E);
    k_scan2<<<2, 1024, 0, stream>>>(cnt_dst, row_dst, cur_dst,
                                    cnt_src, row_src, cur_src, N);
    k_edge_fill<<<(E + 255) / 256, 256, 0, stream>>>(F(0), F(1), ei, tab, z,
                                                     cur_dst, cur_src,
                                                     rec_dst, col_dst, rec_src, E);

    int nb = (N + 3) / 4;
    k_aggr<<<nb, 256, 0, stream>>>(row_src, rec_src, z, tab, F(3), F(2),
                                   F(6), F(7), sbuf, vbuf, N);
    for (int li = 0; li < 4; ++li) {
        k_msg<<<nb, 256, 0, stream>>>(row_dst, rec_dst, col_dst, sbuf, vbuf,
                                      F(14) + li * 32 * 32, F(15) + li * 16 * 32,
                                      F(16) + li * 32 * 16, F(17) + li * 16 * 16,
                                      F(18) + li * 16 * 16, msbuf, mvbuf, N);
        k_node<<<nb, 256, 0, stream>>>(sbuf, vbuf, msbuf, mvbuf,
                                       F(19) + li * 32 * 32, F(20) + li * 16 * 16,
                                       F(21) + li * 32 * 48, F(22) + li * 16 * 16,
                                       F(23) + li * 32 * 32, F(24) + li * 16 * 16,
                                       F(25) + li * 32, F(26) + li * 32,
                                       F(27) + li * 16 * 16, F(28) + li * 16,
                                       F(29) + li * 16 * 32, F(30) + li * 32, N);
    }
    k_out<<<(N * 80 + 255) / 256, 256, 0, stream>>>(sbuf, vbuf, (float*)d_out, N);
}